// Round 9
// baseline (99.793 us; speedup 1.0000x reference)
//
#include <hip/hip_runtime.h>

#define IN_CH  64
#define OUT_CH 32
#define BLOCK  8
#define ROWS   8     // rows per LDS gather tile

// ws layout:
//   [0]        cur[16]  ints (bucket cursors; cur[j] == cnt[j] after k_fill)
//   [256]      argmax   M ints
//   [256+4M]   bm       9*M ints   (bucket j's rows at bm[j*M .. j*M+cnt[j]))
//   [256+40M]  bn       9*M ints

__global__ void k_prep(int4* __restrict__ argmax4, int n4, int* __restrict__ cur) {
    int i = blockIdx.x * 256 + threadIdx.x;
    if (i < 16) cur[i] = 0;
    if (i < n4) argmax4[i] = make_int4(-1, -1, -1, -1);
}

// argmax[m] monotone non-decreasing => stale read is a valid lower bound;
// filtered atomicMax is always correct. Dispatch split makes pass-1 results
// visible so pass-2 filters ~all its atomics.
__global__ void k_scatter_range(const int* __restrict__ pair, int* __restrict__ argmax,
                                int N, int jhi, int jlo, int flip) {
    int n = blockIdx.x * 256 + threadIdx.x;
    if (n >= N) return;
    if (flip) n = N - 1 - n;        // high-t first (execution order ~ blockIdx)
    for (int j = jhi; j >= jlo; --j) {
        int t = j * N + n;
        int m = pair[t];
        if (m >= 0 && argmax[m] < t)
            atomicMax(&argmax[m], t);
    }
}

// bucket rows by j (fixed regions, per-block LDS hist -> 9 atomics/block)
__global__ void k_fill(const int* __restrict__ argmax, int* __restrict__ cur,
                       int* __restrict__ bm, int* __restrict__ bn, int M, int N) {
    __shared__ int h9[9];
    __shared__ int b9[9];
    if (threadIdx.x < 9) h9[threadIdx.x] = 0;
    __syncthreads();
    int m = blockIdx.x * 256 + threadIdx.x;
    int j = 9, n = 0, lo = 0;
    if (m < M) {
        int t = argmax[m];
        if (t >= 0) { j = (int)((unsigned)t / (unsigned)N); n = t - j * N; }
        else j = 8;
        lo = atomicAdd(&h9[j], 1);
    }
    __syncthreads();
    if (threadIdx.x < 9 && h9[threadIdx.x] > 0)
        b9[threadIdx.x] = atomicAdd(&cur[threadIdx.x], h9[threadIdx.x]);
    __syncthreads();
    if (m < M) {
        int pos = j * M + b9[j] + lo;
        bm[pos] = m;
        bn[pos] = n;
    }
}

__global__ __launch_bounds__(512, 4) void k_compute(
        const float* __restrict__ x, const float* __restrict__ w,
        const int* __restrict__ cnt, const int* __restrict__ bm,
        const int* __restrict__ bn, float* __restrict__ out, int M, int N) {
    __shared__ __align__(16) float Xl[8][2][ROWS * 64];   // 32 KB: per-wave dbuf

    const int lane = threadIdx.x & 63;
    const int o    = lane & 31;
    const int hh   = lane >> 5;
    const int wv   = threadIdx.x >> 6;

    // tile id -> (bucket j, local tile T); tiles enumerated per bucket, so
    // wave count per bucket is proportional to its size (no imbalance).
    int T = blockIdx.x * 8 + wv;
    int j = 0, nrows = 0;
    for (; j < 9; ++j) {
        int c  = cnt[j];
        int nt = (c + 63) >> 6;
        if (T < nt) { nrows = min(64, c - T * 64); break; }
        T -= nt;
    }
    if (j >= 9) return;
    int base = j * M + T * 64;

    // W[j] for this lane's (o, 32-ch half) -> 32 VGPRs. j is wave-uniform:
    // zero LDS weight traffic in the row loop.
    int jw = (j < 8) ? j : 0;                  // j==8 rows output zeros
    float4 wreg[8];
#pragma unroll
    for (int k = 0; k < 8; ++k)
        wreg[k] = *(const float4*)&w[(o * BLOCK + jw) * IN_CH + hh * 32 + k * 4];

    int mm = 0, nn = 0;
    if (lane < nrows) { mm = bm[base + lane]; nn = bn[base + lane]; }

    int ntiles = (nrows + ROWS - 1) / ROWS;
    float ld[ROWS];

    // prologue: tile-0 gathers — one coalesced 256B row per instr, addresses
    // via v_readlane (SGPR base), 8 independent loads in flight
#pragma unroll
    for (int r = 0; r < ROWS; ++r) {
        int n = __builtin_amdgcn_readlane(nn, r);
        ld[r] = x[(size_t)n * IN_CH + lane];
    }

    for (int tile = 0; tile < ntiles; ++tile) {
        float* buf = &Xl[wv][tile & 1][0];
#pragma unroll
        for (int r = 0; r < ROWS; ++r)
            buf[r * 64 + lane] = ld[r];

        if (tile + 1 < ntiles) {
            int nb = (tile + 1) * ROWS;
#pragma unroll
            for (int r = 0; r < ROWS; ++r) {
                int n = __builtin_amdgcn_readlane(nn, nb + r);
                ld[r] = x[(size_t)n * IN_CH + lane];
            }
        }

        // wave-private LDS: no barrier, just drain ds_writes
        asm volatile("s_waitcnt lgkmcnt(0)" ::: "memory");

#pragma unroll
        for (int r = 0; r < ROWS; r += 2) {
            int grow = tile * ROWS + r;
            float s01[2];
#pragma unroll
            for (int p = 0; p < 2; ++p) {
                const float4* xp = (const float4*)(buf + (r + p) * 64) + hh * 8;
                float ax = 0.f, ay = 0.f, az = 0.f, aw = 0.f;
#pragma unroll
                for (int k = 0; k < 8; ++k) {
                    float4 xv = xp[k];            // 2-addr broadcast read (cheap)
                    ax = fmaf(wreg[k].x, xv.x, ax);
                    ay = fmaf(wreg[k].y, xv.y, ay);
                    az = fmaf(wreg[k].z, xv.z, az);
                    aw = fmaf(wreg[k].w, xv.w, aw);
                }
                float s = (ax + ay) + (az + aw);
                s += __shfl_xor(s, 32);           // combine c-halves
                s01[p] = s;
            }
            // both half-waves store: h=0 -> row grow, h=1 -> row grow+1
            float sv   = hh ? s01[1] : s01[0];
            int   m0   = __builtin_amdgcn_readlane(mm, grow);
            int   m1   = __builtin_amdgcn_readlane(mm, grow + 1);
            int   mrow = hh ? m1 : m0;
            if (j == 8) sv = 0.f;                 // unmapped rows -> exact 0
            int orow = grow + hh;
            if (orow < nrows)
                out[(size_t)mrow * OUT_CH + o] = sv;
        }
    }
}

extern "C" void kernel_launch(void* const* d_in, const int* in_sizes, int n_in,
                              void* d_out, int out_size, void* d_ws, size_t ws_size,
                              hipStream_t stream) {
    const float* x    = (const float*)d_in[0];
    const float* w    = (const float*)d_in[1];
    const int*   pair = (const int*)d_in[2];
    int N = in_sizes[0] / IN_CH;     // 400000
    int M = out_size / OUT_CH;       // 200000

    char* ws     = (char*)d_ws;
    int*  cur    = (int*)ws;
    int*  argmax = (int*)(ws + 256);
    int*  bm     = (int*)(ws + 256 + (size_t)M * 4);
    int*  bn     = (int*)(ws + 256 + (size_t)M * 4 + (size_t)9 * M * 4);

    int n4 = M / 4;                  // M % 4 == 0
    k_prep<<<(n4 + 255) / 256, 256, 0, stream>>>((int4*)argmax, n4, cur);

    int gN = (N + 255) / 256;
    k_scatter_range<<<gN, 256, 0, stream>>>(pair, argmax, N, 7, 7, 1); // j=7 first
    k_scatter_range<<<gN, 256, 0, stream>>>(pair, argmax, N, 6, 0, 0); // rest, filtered

    k_fill<<<(M + 255) / 256, 256, 0, stream>>>(argmax, cur, bm, bn, M, N);

    int maxtiles = (M + 63) / 64 + 8;                 // worst case across buckets
    int blocks   = (maxtiles + 7) / 8;
    k_compute<<<blocks, 512, 0, stream>>>(x, w, cur, bm, bn, (float*)d_out, M, N);
}

// Round 10
// 91.297 us; speedup vs baseline: 1.0931x; 1.0931x over previous
//
#include <hip/hip_runtime.h>

#define IN_CH  64
#define OUT_CH 32
#define BLOCK  8

using short8 = __attribute__((ext_vector_type(8))) short;
using f32x4v = __attribute__((ext_vector_type(4))) float;

// ws layout:
//   [0]        cur[16]  ints (bucket cursors; cur[j] == cnt[j] after k_fill)
//   [256]      argmax   M ints
//   [256+4M]   bm       9*M ints   (bucket j's rows at bm[j*M .. j*M+cnt[j]))
//   [256+40M]  bn       9*M ints

__global__ void k_prep(int4* __restrict__ argmax4, int n4, int* __restrict__ cur) {
    int i = blockIdx.x * 256 + threadIdx.x;
    if (i < 16) cur[i] = 0;
    if (i < n4) argmax4[i] = make_int4(-1, -1, -1, -1);
}

// argmax[m] monotone non-decreasing => stale read is a valid lower bound;
// filtered atomicMax is always correct. Dispatch split makes pass-1 results
// visible so pass-2 filters ~all its atomics.
__global__ void k_scatter_range(const int* __restrict__ pair, int* __restrict__ argmax,
                                int N, int jhi, int jlo, int flip) {
    int n = blockIdx.x * 256 + threadIdx.x;
    if (n >= N) return;
    if (flip) n = N - 1 - n;        // high-t first (execution order ~ blockIdx)
    for (int j = jhi; j >= jlo; --j) {
        int t = j * N + n;
        int m = pair[t];
        if (m >= 0 && argmax[m] < t)
            atomicMax(&argmax[m], t);
    }
}

// bucket rows by j (fixed regions, per-block LDS hist -> 9 atomics/block)
__global__ void k_fill(const int* __restrict__ argmax, int* __restrict__ cur,
                       int* __restrict__ bm, int* __restrict__ bn, int M, int N) {
    __shared__ int h9[9];
    __shared__ int b9[9];
    if (threadIdx.x < 9) h9[threadIdx.x] = 0;
    __syncthreads();
    int m = blockIdx.x * 256 + threadIdx.x;
    int j = 9, n = 0, lo = 0;
    if (m < M) {
        int t = argmax[m];
        if (t >= 0) { j = (int)((unsigned)t / (unsigned)N); n = t - j * N; }
        else j = 8;
        lo = atomicAdd(&h9[j], 1);
    }
    __syncthreads();
    if (threadIdx.x < 9 && h9[threadIdx.x] > 0)
        b9[threadIdx.x] = atomicAdd(&cur[threadIdx.x], h9[threadIdx.x]);
    __syncthreads();
    if (m < M) {
        int pos = j * M + b9[j] + lo;
        bm[pos] = m;
        bn[pos] = n;
    }
}

__device__ __forceinline__ unsigned cvt_pk_bf16(float lo, float hi) {
    unsigned r;
    asm("v_cvt_pk_bf16_f32 %0, %1, %2" : "=v"(r) : "v"(lo), "v"(hi));
    return r;
}

__device__ __forceinline__ short8 pack8(float4 a, float4 b) {
    union { unsigned u[4]; short8 s; } p;
    p.u[0] = cvt_pk_bf16(a.x, a.y);
    p.u[1] = cvt_pk_bf16(a.z, a.w);
    p.u[2] = cvt_pk_bf16(b.x, b.y);
    p.u[3] = cvt_pk_bf16(b.z, b.w);
    return p.s;
}

// MFMA GEMM per bucket: out[m,o] = sum_c W[o,j,c] * x[n,c], j wave-uniform.
// A (x tile, 16x32): lane holds row=lane&15, k=(lane>>4)*8+e  (2x 32B loads)
// B (W^T slice, 32x16): lane holds k=(lane>>4)*8+e, col(o)=lane&15
// C/D: col=lane&15, row=(lane>>4)*4+q   [m89-verified layout]
// No LDS at all -- kills the 8KB/row LDS broadcast amplification.
__global__ __launch_bounds__(256, 4) void k_compute(
        const float* __restrict__ x, const float* __restrict__ w,
        const int* __restrict__ cnt, const int* __restrict__ bm,
        const int* __restrict__ bn, float* __restrict__ out, int M, int N) {
    const int lane = threadIdx.x & 63;
    const int r16  = lane & 15;     // A row / B,C col
    const int kc   = lane >> 4;     // k-chunk; C row group
    const int wv   = threadIdx.x >> 6;

    // wave -> (bucket j, 64-row tile T); tiles enumerated per bucket
    int T = blockIdx.x * 4 + wv;
    int j = 0, nrows = 0;
    for (; j < 9; ++j) {
        int c  = cnt[j];
        int nt = (c + 63) >> 6;
        if (T < nt) { nrows = min(64, c - T * 64); break; }
        T -= nt;
    }
    if (j >= 9) return;
    int base = j * M + T * 64;
    int jw = (j < 8) ? j : 0;       // j==8 rows output zeros

    // B fragments: 2 o-tiles x 2 k-halves, 16 VGPRs total, loaded once
    short8 bf[2][2];
#pragma unroll
    for (int ot = 0; ot < 2; ++ot)
#pragma unroll
        for (int kk = 0; kk < 2; ++kk) {
            const float* wp = w + ((ot * 16 + r16) * BLOCK + jw) * IN_CH + kk * 32 + kc * 8;
            bf[ot][kk] = pack8(*(const float4*)wp, *(const float4*)(wp + 4));
        }

#pragma unroll
    for (int st = 0; st < 4; ++st) {
        if (st * 16 >= nrows) break;
        int lrow = st * 16 + r16;
        int n    = bn[base + ((lrow < nrows) ? lrow : 0)];
        const float* xp = x + (size_t)n * IN_CH + kc * 8;
        float4 x0 = *(const float4*)xp;
        float4 x1 = *(const float4*)(xp + 4);
        float4 x2 = *(const float4*)(xp + 32);
        float4 x3 = *(const float4*)(xp + 36);
        short8 a0 = pack8(x0, x1);            // k 0..31 slice
        short8 a1 = pack8(x2, x3);            // k 32..63 slice

        f32x4v acc0 = {0.f, 0.f, 0.f, 0.f};
        f32x4v acc1 = {0.f, 0.f, 0.f, 0.f};
        acc0 = __builtin_amdgcn_mfma_f32_16x16x32_bf16(a0, bf[0][0], acc0, 0, 0, 0);
        acc0 = __builtin_amdgcn_mfma_f32_16x16x32_bf16(a1, bf[0][1], acc0, 0, 0, 0);
        acc1 = __builtin_amdgcn_mfma_f32_16x16x32_bf16(a0, bf[1][0], acc1, 0, 0, 0);
        acc1 = __builtin_amdgcn_mfma_f32_16x16x32_bf16(a1, bf[1][1], acc1, 0, 0, 0);

        int4 m4 = *(const int4*)&bm[base + st * 16 + kc * 4];
        int ma[4] = {m4.x, m4.y, m4.z, m4.w};
#pragma unroll
        for (int q = 0; q < 4; ++q) {
            int grow = st * 16 + kc * 4 + q;
            if (grow < nrows) {
                size_t ro = (size_t)ma[q] * OUT_CH;
                float v0 = (j == 8) ? 0.f : acc0[q];
                float v1 = (j == 8) ? 0.f : acc1[q];
                out[ro + r16]      = v0;      // 4x 64B segments per instr
                out[ro + 16 + r16] = v1;
            }
        }
    }
}

extern "C" void kernel_launch(void* const* d_in, const int* in_sizes, int n_in,
                              void* d_out, int out_size, void* d_ws, size_t ws_size,
                              hipStream_t stream) {
    const float* x    = (const float*)d_in[0];
    const float* w    = (const float*)d_in[1];
    const int*   pair = (const int*)d_in[2];
    int N = in_sizes[0] / IN_CH;     // 400000
    int M = out_size / OUT_CH;       // 200000

    char* ws     = (char*)d_ws;
    int*  cur    = (int*)ws;
    int*  argmax = (int*)(ws + 256);
    int*  bm     = (int*)(ws + 256 + (size_t)M * 4);
    int*  bn     = (int*)(ws + 256 + (size_t)M * 4 + (size_t)9 * M * 4);

    int n4 = M / 4;                  // M % 4 == 0
    k_prep<<<(n4 + 255) / 256, 256, 0, stream>>>((int4*)argmax, n4, cur);

    int gN = (N + 255) / 256;
    k_scatter_range<<<gN, 256, 0, stream>>>(pair, argmax, N, 7, 7, 1); // j=7 first
    k_scatter_range<<<gN, 256, 0, stream>>>(pair, argmax, N, 6, 0, 0); // rest, filtered

    k_fill<<<(M + 255) / 256, 256, 0, stream>>>(argmax, cur, bm, bn, M, N);

    int maxtiles = (M + 63) / 64 + 9;                 // worst case across buckets
    int blocks   = (maxtiles + 3) / 4;                // 4 waves / 256-thread block
    k_compute<<<blocks, 256, 0, stream>>>(x, w, cur, bm, bn, (float*)d_out, M, N);
}